// Round 5
// baseline (752.131 us; speedup 1.0000x reference)
//
#include <hip/hip_runtime.h>
#include <hip/hip_bf16.h>
#include <cstdint>

#define BN_EPS 1e-5f

typedef __attribute__((ext_vector_type(8))) short short8;
typedef __attribute__((ext_vector_type(8))) __bf16 bf16x8;
typedef __attribute__((ext_vector_type(4))) float f32x4;

__device__ inline short f2bf(float f) {
    union { float f; unsigned u; } v; v.f = f;
    unsigned r = v.u + 0x7fffu + ((v.u >> 16) & 1u); // RNE
    return (short)(r >> 16);
}
__device__ inline float bf2f(short h) {
    union { unsigned u; float f; } v;
    v.u = ((unsigned)(unsigned short)h) << 16;
    return v.f;
}

// ---------------- setup kernels ----------------

__global__ void zero_kernel(float* stats, int nstats, int* deg, int N) {
    int i = blockIdx.x * 256 + threadIdx.x;
    if (i < nstats) stats[i] = 0.f;
    if (i < N) deg[i] = 0;
}

// transpose + bf16 split weights: WtHi/WtLo[mat][n][k] = split(W[mat][k][n])
__global__ void tw_kernel(const float* __restrict__ W1, const float* __restrict__ W2,
                          short* __restrict__ WtHi, short* __restrict__ WtLo) {
    int t = blockIdx.x * 256 + threadIdx.x;
    if (t >= 10 * 128 * 128) return;
    int mat = t >> 14, n = (t >> 7) & 127, k = t & 127;
    const float* W = (mat < 5) ? (W1 + mat * 16384) : (W2 + (mat - 5) * 16384);
    float w = W[k * 128 + n];
    short hi = f2bf(w);
    WtHi[t] = hi;
    WtLo[t] = f2bf(w - bf2f(hi));
}

__global__ void count_kernel(const int* __restrict__ dst, int* __restrict__ deg, int E) {
    int e = blockIdx.x * 256 + threadIdx.x;
    if (e < E) atomicAdd(&deg[dst[e]], 1);
}

// ---- multi-block exclusive scan of deg -> rowptr/cursor ----

__global__ __launch_bounds__(256) void scanA_kernel(const int* __restrict__ deg,
                                                    int* __restrict__ blockSums, int N) {
    int t = threadIdx.x, b = blockIdx.x;
    int base = b * 1024 + t * 4;
    int s = 0;
#pragma unroll
    for (int k = 0; k < 4; ++k) { int i = base + k; if (i < N) s += deg[i]; }
#pragma unroll
    for (int off = 1; off < 64; off <<= 1) s += __shfl_xor(s, off, 64);
    __shared__ int ws[4];
    if ((t & 63) == 0) ws[t >> 6] = s;
    __syncthreads();
    if (t == 0) blockSums[b] = ws[0] + ws[1] + ws[2] + ws[3];
}

__global__ __launch_bounds__(256) void scanB_kernel(int* __restrict__ blockSums,
                                                    int* __restrict__ rowptrN, int nb) {
    __shared__ int ps[256];
    int t = threadIdx.x;
    int v = (t < nb) ? blockSums[t] : 0;
    ps[t] = v;
    __syncthreads();
#pragma unroll
    for (int off = 1; off < 256; off <<= 1) {
        int u = 0;
        if (t >= off) u = ps[t - off];
        __syncthreads();
        ps[t] += u;
        __syncthreads();
    }
    if (t < nb) blockSums[t] = ps[t] - v;
    if (t == 255) rowptrN[0] = ps[255];
}

__global__ __launch_bounds__(256) void scanC_kernel(const int* __restrict__ deg,
                                                    const int* __restrict__ blockSums,
                                                    int* __restrict__ rowptr,
                                                    int* __restrict__ cursor, int N) {
    __shared__ int ps[256];
    int t = threadIdx.x, b = blockIdx.x;
    int base = b * 1024 + t * 4;
    int d[4];
    int s = 0;
#pragma unroll
    for (int k = 0; k < 4; ++k) {
        d[k] = (base + k < N) ? deg[base + k] : 0;
        s += d[k];
    }
    int local = s;
    ps[t] = s;
    __syncthreads();
#pragma unroll
    for (int off = 1; off < 256; off <<= 1) {
        int u = 0;
        if (t >= off) u = ps[t - off];
        __syncthreads();
        ps[t] += u;
        __syncthreads();
    }
    int pre = ps[t] - local + blockSums[b];
#pragma unroll
    for (int k = 0; k < 4; ++k) {
        int i = base + k;
        if (i < N) { rowptr[i] = pre; cursor[i] = pre; pre += d[k]; }
    }
}

__global__ void fill_kernel(const int* __restrict__ src, const int* __restrict__ dst,
                            int* __restrict__ cursor, int* __restrict__ colidx, int E) {
    int e = blockIdx.x * 256 + threadIdx.x;
    if (e < E) {
        int p = atomicAdd(&cursor[dst[e]], 1);
        colidx[p] = src[e];
    }
}

// coeff from striped stats [8][256]: a = g*rsqrt(var+eps), c = b - mean*a
__device__ inline void coeff_from_stats(const float* __restrict__ stats,
                                        const float* __restrict__ g,
                                        const float* __restrict__ bb,
                                        int col, int N, float& a, float& c) {
    float s = 0.f, q = 0.f;
#pragma unroll
    for (int st = 0; st < 8; ++st) {
        s += stats[st * 256 + col];
        q += stats[st * 256 + 128 + col];
    }
    float m = s / N, v = q / N - m * m;
    a = g[col] * rsqrtf(v + BN_EPS);
    c = bb[col] - m * a;
}

// ---------------- aggregation: rst[i] = f(x[i]) + sum_{j in in(i)} f(x[j]) ----------------
// MODE 0: f = identity. MODE 1: f(u) = relu(a3*relu(a2*u+c2)+c3), coeffs inline from stats.
// One wave handles 8 consecutive nodes; lane covers cols 2*lane, 2*lane+1. Edge unroll x8.

template <int MODE>
__global__ __launch_bounds__(256) void agg_kernel(
    const float* __restrict__ Xf, const int* __restrict__ rowptr,
    const int* __restrict__ colidx,
    const float* __restrict__ stats2, const float* __restrict__ g2, const float* __restrict__ b2v,
    const float* __restrict__ stats3, const float* __restrict__ g3, const float* __restrict__ b3v,
    float* __restrict__ rst, int N) {
    __shared__ float cf[4][128];
    int t = threadIdx.x;
    if (MODE) {
        if (t < 128) {
            float a, c;
            coeff_from_stats(stats2, g2, b2v, t, N, a, c);
            cf[0][t] = a; cf[1][t] = c;
            coeff_from_stats(stats3, g3, b3v, t, N, a, c);
            cf[2][t] = a; cf[3][t] = c;
        }
        __syncthreads();
    }
    int lane = t & 63;
    int c0 = lane * 2, c1 = c0 + 1;
    float a2x = 1.f, c2x = 0.f, a2y = 1.f, c2y = 0.f;
    float a3x = 1.f, c3x = 0.f, a3y = 1.f, c3y = 0.f;
    if (MODE) {
        a2x = cf[0][c0]; a2y = cf[0][c1]; c2x = cf[1][c0]; c2y = cf[1][c1];
        a3x = cf[2][c0]; a3y = cf[2][c1]; c3x = cf[3][c0]; c3y = cf[3][c1];
    }
    auto fx = [&](float u) {
        if (MODE == 0) return u;
        float z = fmaxf(a2x * u + c2x, 0.f);
        return fmaxf(a3x * z + c3x, 0.f);
    };
    auto fy = [&](float u) {
        if (MODE == 0) return u;
        float z = fmaxf(a2y * u + c2y, 0.f);
        return fmaxf(a3y * z + c3y, 0.f);
    };
    const float2* X2 = (const float2*)Xf;
    int wv = __builtin_amdgcn_readfirstlane(t >> 6);
    int nodeBase = (blockIdx.x * 4 + wv) * 8;
    for (int i = 0; i < 8; ++i) {
        int node = nodeBase + i;
        if (node >= N) break;
        float2 self = X2[(size_t)node * 64 + lane];
        float ax = fx(self.x), ay = fy(self.y);
        int e = rowptr[node], end = rowptr[node + 1];
        for (; e + 8 <= end; e += 8) {
            int j[8];
#pragma unroll
            for (int k = 0; k < 8; ++k) j[k] = colidx[e + k];
            float2 v[8];
#pragma unroll
            for (int k = 0; k < 8; ++k) v[k] = X2[(size_t)j[k] * 64 + lane];
#pragma unroll
            for (int k = 0; k < 8; ++k) { ax += fx(v[k].x); ay += fy(v[k].y); }
        }
        for (; e < end; ++e) {
            int j = colidx[e];
            float2 v = X2[(size_t)j * 64 + lane];
            ax += fx(v.x);
            ay += fy(v.y);
        }
        float2 r; r.x = ax; r.y = ay;
        ((float2*)rst)[(size_t)node * 64 + lane] = r;
    }
}

// ---------------- GEMM: C = pre(A) @ W + bias, striped column stats ----------------
// W hi/lo staged in LDS (XOR-swizzled); A streamed global->registers with split conversion.
// PRE==1: relu(a*x+c); coeffs computed per-lane (2 cols each) from striped stats, then
// redistributed via __shfl (no extra LDS — Ws is at the 64 KB static cap).

template <int PRE>
__global__ __launch_bounds__(256, 2) void gemm_kernel(
    const float* __restrict__ A,
    const short* __restrict__ WtHi, const short* __restrict__ WtLo,
    const float* __restrict__ bias,
    const float* __restrict__ preStats, const float* __restrict__ preG,
    const float* __restrict__ preB,
    float* __restrict__ C, float* __restrict__ outStats, int N) {
    __shared__ short WsHi[128 * 128];
    __shared__ short WsLo[128 * 128];

    const int t = threadIdx.x;
    const int row0 = blockIdx.x * 128;
    const int w = t >> 6, lane = t & 63;
    const int quad = lane >> 4, l16 = lane & 15;
    const int sw = (l16 & 7) * 8;

    // coeffs for cols lane*2 (E) and lane*2+1 (O)
    float aE = 1.f, cE = 0.f, aO = 1.f, cO = 0.f;
    if (PRE) {
        coeff_from_stats(preStats, preG, preB, lane * 2, N, aE, cE);
        coeff_from_stats(preStats, preG, preB, lane * 2 + 1, N, aO, cO);
    }

    // phase 1: A f32 loads (rows w*32+l16, w*32+16+l16)
    float4 af[2][4][2];
#pragma unroll
    for (int m = 0; m < 2; ++m) {
        int gr = row0 + w * 32 + m * 16 + l16;
        bool ok = gr < N;
        const float* Ar = A + (size_t)gr * 128;
#pragma unroll
        for (int kk = 0; kk < 4; ++kk) {
            int kb = kk * 32 + quad * 8;
            af[m][kk][0] = ok ? *(const float4*)(Ar + kb) : make_float4(0.f, 0.f, 0.f, 0.f);
            af[m][kk][1] = ok ? *(const float4*)(Ar + kb + 4) : make_float4(0.f, 0.f, 0.f, 0.f);
        }
    }

    // phase 2: stage W hi/lo into LDS, XOR-swizzled rows
#pragma unroll
    for (int i = 0; i < 8; ++i) {
        int ch = t + i * 256;
        int r = ch >> 4, k = (ch & 15) * 8;
        int d = r * 128 + (k ^ ((r & 7) * 8));
        *(short8*)(WsHi + d) = *(const short8*)(WtHi + r * 128 + k);
        *(short8*)(WsLo + d) = *(const short8*)(WtLo + r * 128 + k);
    }
    __syncthreads();

    // phase 3: BN + split-convert A fragments (coeffs via shuffle)
    short8 fh[2][4], fl[2][4];
#pragma unroll
    for (int kk = 0; kk < 4; ++kk) {
        float a8[8], c8[8];
#pragma unroll
        for (int j = 0; j < 8; ++j) {
            if (PRE) {
                int col = kk * 32 + quad * 8 + j;
                int srcl = col >> 1;
                a8[j] = __shfl((j & 1) ? aO : aE, srcl, 64);
                c8[j] = __shfl((j & 1) ? cO : cE, srcl, 64);
            }
        }
#pragma unroll
        for (int m = 0; m < 2; ++m) {
            float x[8];
            *(float4*)(x) = af[m][kk][0];
            *(float4*)(x + 4) = af[m][kk][1];
            short8 h, lo;
#pragma unroll
            for (int j = 0; j < 8; ++j) {
                float y = PRE ? fmaxf(a8[j] * x[j] + c8[j], 0.f) : x[j];
                short hi = f2bf(y);
                h[j] = hi;
                lo[j] = f2bf(y - bf2f(hi));
            }
            fh[m][kk] = h;
            fl[m][kk] = lo;
        }
    }

    f32x4 acc[2][8];
#pragma unroll
    for (int m = 0; m < 2; ++m)
#pragma unroll
        for (int n = 0; n < 8; ++n) acc[m][n] = (f32x4){0.f, 0.f, 0.f, 0.f};

#pragma unroll
    for (int kk = 0; kk < 4; ++kk) {
        int kb = kk * 32 + quad * 8;
        bf16x8 a0h = __builtin_bit_cast(bf16x8, fh[0][kk]);
        bf16x8 a1h = __builtin_bit_cast(bf16x8, fh[1][kk]);
        bf16x8 a0l = __builtin_bit_cast(bf16x8, fl[0][kk]);
        bf16x8 a1l = __builtin_bit_cast(bf16x8, fl[1][kk]);
#pragma unroll
        for (int n = 0; n < 8; ++n) {
            int woff = (n * 16 + l16) * 128 + (kb ^ sw);
            bf16x8 bh = __builtin_bit_cast(bf16x8, *(const short8*)(WsHi + woff));
            bf16x8 bl = __builtin_bit_cast(bf16x8, *(const short8*)(WsLo + woff));
            acc[0][n] = __builtin_amdgcn_mfma_f32_16x16x32_bf16(a0h, bh, acc[0][n], 0, 0, 0);
            acc[0][n] = __builtin_amdgcn_mfma_f32_16x16x32_bf16(a0l, bh, acc[0][n], 0, 0, 0);
            acc[0][n] = __builtin_amdgcn_mfma_f32_16x16x32_bf16(a0h, bl, acc[0][n], 0, 0, 0);
            acc[1][n] = __builtin_amdgcn_mfma_f32_16x16x32_bf16(a1h, bh, acc[1][n], 0, 0, 0);
            acc[1][n] = __builtin_amdgcn_mfma_f32_16x16x32_bf16(a1l, bh, acc[1][n], 0, 0, 0);
            acc[1][n] = __builtin_amdgcn_mfma_f32_16x16x32_bf16(a1h, bl, acc[1][n], 0, 0, 0);
        }
    }

    __syncthreads(); // all LDS reads done; WsHi reused below for stats reduction

    float bv[8];
#pragma unroll
    for (int n = 0; n < 8; ++n) bv[n] = bias[n * 16 + l16];
    float ls[8], lsq[8];
#pragma unroll
    for (int n = 0; n < 8; ++n) { ls[n] = 0.f; lsq[n] = 0.f; }
#pragma unroll
    for (int m = 0; m < 2; ++m) {
        int rbase = row0 + w * 32 + m * 16 + quad * 4;
#pragma unroll
        for (int n = 0; n < 8; ++n) {
            int colv = n * 16 + l16;
#pragma unroll
            for (int r = 0; r < 4; ++r) {
                int row = rbase + r;
                if (row < N) {
                    float val = acc[m][n][r] + bv[n];
                    C[(size_t)row * 128 + colv] = val;
                    ls[n] += val;
                    lsq[n] += val * val;
                }
            }
        }
    }

    float* P = (float*)WsHi;
#pragma unroll
    for (int n = 0; n < 8; ++n) {
        float s = ls[n], q = lsq[n];
        s += __shfl_xor(s, 16, 64);
        s += __shfl_xor(s, 32, 64);
        q += __shfl_xor(q, 16, 64);
        q += __shfl_xor(q, 32, 64);
        if (quad == 0) {
            int colv = n * 16 + l16;
            P[w * 512 + colv] = s;
            P[w * 512 + 256 + colv] = q;
        }
    }
    __syncthreads();

    int stripe = blockIdx.x & 7;
    if (t < 128) {
        int col = t;
        float S = P[col] + P[512 + col] + P[1024 + col] + P[1536 + col];
        atomicAdd(&outStats[stripe * 256 + col], S);
    } else {
        int col = t - 128;
        float Q = P[256 + col] + P[768 + col] + P[1280 + col] + P[1792 + col];
        atomicAdd(&outStats[stripe * 256 + 128 + col], Q);
    }
}

// ---------------- stats of y = relu(a*x+c) (no materialization), striped ----------------

__global__ __launch_bounds__(256) void elt_kernel(
    const float* __restrict__ X,
    const float* __restrict__ inStats, const float* __restrict__ g, const float* __restrict__ bb,
    float* __restrict__ outStats, int N) {
    __shared__ float red[256 * 8];
    __shared__ float cf[2][128];
    int t = threadIdx.x;
    if (t < 128) {
        float a, c;
        coeff_from_stats(inStats, g, bb, t, N, a, c);
        cf[0][t] = a; cf[1][t] = c;
    }
    __syncthreads();
    int cg = t & 31;
    float a[4], c[4];
#pragma unroll
    for (int k = 0; k < 4; ++k) {
        a[k] = cf[0][cg * 4 + k];
        c[k] = cf[1][cg * 4 + k];
    }
    float sum[4] = {0.f, 0.f, 0.f, 0.f}, sq[4] = {0.f, 0.f, 0.f, 0.f};
    int total = N * 32;
    for (int i = blockIdx.x * 256 + t; i < total; i += gridDim.x * 256) {
        float4 v = ((const float4*)X)[i];
        float4 y;
        y.x = fmaxf(a[0] * v.x + c[0], 0.f);
        y.y = fmaxf(a[1] * v.y + c[1], 0.f);
        y.z = fmaxf(a[2] * v.z + c[2], 0.f);
        y.w = fmaxf(a[3] * v.w + c[3], 0.f);
        sum[0] += y.x; sq[0] += y.x * y.x;
        sum[1] += y.y; sq[1] += y.y * y.y;
        sum[2] += y.z; sq[2] += y.z * y.z;
        sum[3] += y.w; sq[3] += y.w * y.w;
    }
#pragma unroll
    for (int k = 0; k < 4; ++k) { red[t * 8 + k] = sum[k]; red[t * 8 + 4 + k] = sq[k]; }
    __syncthreads();
    if (t < 32) {
        float S[4] = {0.f, 0.f, 0.f, 0.f}, Q[4] = {0.f, 0.f, 0.f, 0.f};
        for (int j = 0; j < 8; ++j) {
            int tt = t + 32 * j;
#pragma unroll
            for (int k = 0; k < 4; ++k) { S[k] += red[tt * 8 + k]; Q[k] += red[tt * 8 + 4 + k]; }
        }
        int stripe = blockIdx.x & 7;
#pragma unroll
        for (int k = 0; k < 4; ++k) {
            atomicAdd(&outStats[stripe * 256 + t * 4 + k], S[k]);
            atomicAdd(&outStats[stripe * 256 + 128 + t * 4 + k], Q[k]);
        }
    }
}

// ---------------- final: out = relu(a3*relu(a2*x+c2)+c3), coeffs inline ----------------

__global__ __launch_bounds__(256) void final_kernel(
    const float* __restrict__ X,
    const float* __restrict__ stats2, const float* __restrict__ g2, const float* __restrict__ b2v,
    const float* __restrict__ stats3, const float* __restrict__ g3, const float* __restrict__ b3v,
    float* __restrict__ out, int N) {
    __shared__ float cf[4][128];
    int t = threadIdx.x;
    if (t < 128) {
        float a, c;
        coeff_from_stats(stats2, g2, b2v, t, N, a, c);
        cf[0][t] = a; cf[1][t] = c;
        coeff_from_stats(stats3, g3, b3v, t, N, a, c);
        cf[2][t] = a; cf[3][t] = c;
    }
    __syncthreads();
    int cg = t & 31;
    float a2[4], c2[4], a3[4], c3[4];
#pragma unroll
    for (int k = 0; k < 4; ++k) {
        int colv = cg * 4 + k;
        a2[k] = cf[0][colv]; c2[k] = cf[1][colv];
        a3[k] = cf[2][colv]; c3[k] = cf[3][colv];
    }
    int total = N * 32;
    for (int i = blockIdx.x * 256 + t; i < total; i += gridDim.x * 256) {
        float4 v = ((const float4*)X)[i];
        float4 y;
        y.x = fmaxf(a3[0] * fmaxf(a2[0] * v.x + c2[0], 0.f) + c3[0], 0.f);
        y.y = fmaxf(a3[1] * fmaxf(a2[1] * v.y + c2[1], 0.f) + c3[1], 0.f);
        y.z = fmaxf(a3[2] * fmaxf(a2[2] * v.z + c2[2], 0.f) + c3[2], 0.f);
        y.w = fmaxf(a3[3] * fmaxf(a2[3] * v.w + c2[3], 0.f) + c3[3], 0.f);
        ((float4*)out)[i] = y;
    }
}

// ---------------- launch ----------------

extern "C" void kernel_launch(void* const* d_in, const int* in_sizes, int n_in,
                              void* d_out, int out_size, void* d_ws, size_t ws_size,
                              hipStream_t stream) {
    const float* h0   = (const float*)d_in[0];
    const int*   src  = (const int*)d_in[1];
    const int*   dst  = (const int*)d_in[2];
    const float* W1   = (const float*)d_in[3];
    const float* b1   = (const float*)d_in[4];
    const float* W2   = (const float*)d_in[5];
    const float* b2   = (const float*)d_in[6];
    const float* bn1g = (const float*)d_in[7];
    const float* bn1b = (const float*)d_in[8];
    const float* bn2g = (const float*)d_in[9];
    const float* bn2b = (const float*)d_in[10];
    const float* bn3g = (const float*)d_in[11];
    const float* bn3b = (const float*)d_in[12];
    const int N = in_sizes[0] / 128;
    const int E = in_sizes[1];

    char* ws = (char*)d_ws;
    size_t off = 0;
    auto alloc = [&](size_t bytes) {
        void* p = ws + off;
        off = (off + bytes + 255) & ~(size_t)255;
        return p;
    };
    float* stats   = (float*)alloc((size_t)5 * 3 * 8 * 256 * sizeof(float)); // striped
    int*   deg     = (int*)alloc((size_t)N * 4);
    int*   cursor  = (int*)alloc((size_t)N * 4);
    int*   rowptr  = (int*)alloc((size_t)(N + 1) * 4);
    int*   colidx  = (int*)alloc((size_t)E * 4);
    int*   bsums   = (int*)alloc(1024);
    short* WtHi    = (short*)alloc((size_t)10 * 16384 * 2);
    short* WtLo    = (short*)alloc((size_t)10 * 16384 * 2);
    float* buf0    = (float*)alloc((size_t)N * 128 * 4);
    float* buf1    = (float*)alloc((size_t)N * 128 * 4);

    auto statsBase = [&](int l, int which) { return stats + ((size_t)(l * 3 + which)) * 8 * 256; };

    const int nstats = 5 * 3 * 8 * 256;
    int zgrid = ((N > nstats ? N : nstats) + 255) / 256;
    zero_kernel<<<zgrid, 256, 0, stream>>>(stats, nstats, deg, N);
    tw_kernel<<<(10 * 16384 + 255) / 256, 256, 0, stream>>>(W1, W2, WtHi, WtLo);
    count_kernel<<<(E + 255) / 256, 256, 0, stream>>>(dst, deg, E);
    int nb = (N + 1023) / 1024;
    scanA_kernel<<<nb, 256, 0, stream>>>(deg, bsums, N);
    scanB_kernel<<<1, 256, 0, stream>>>(bsums, rowptr + N, nb);
    scanC_kernel<<<nb, 256, 0, stream>>>(deg, bsums, rowptr, cursor, N);
    fill_kernel<<<(E + 255) / 256, 256, 0, stream>>>(src, dst, cursor, colidx, E);

    const int gemmGrid = (N + 127) / 128;
    const int aggGrid = (N + 31) / 32;
    for (int l = 0; l < 5; ++l) {
        float* rstBuf = (l % 2 == 0) ? buf0 : buf1;
        float* x1Buf  = (l % 2 == 0) ? buf1 : buf0;
        float* x2Buf  = rstBuf;
        if (l == 0) {
            agg_kernel<0><<<aggGrid, 256, 0, stream>>>(
                h0, rowptr, colidx,
                nullptr, nullptr, nullptr, nullptr, nullptr, nullptr,
                rstBuf, N);
        } else {
            int lp = l - 1;
            const float* prevX2 = (lp % 2 == 0) ? buf0 : buf1;
            agg_kernel<1><<<aggGrid, 256, 0, stream>>>(
                prevX2, rowptr, colidx,
                statsBase(lp, 1), bn2g + lp * 128, bn2b + lp * 128,
                statsBase(lp, 2), bn3g + lp * 128, bn3b + lp * 128,
                rstBuf, N);
        }
        gemm_kernel<0><<<gemmGrid, 256, 0, stream>>>(
            rstBuf, WtHi + l * 16384, WtLo + l * 16384, b1 + l * 128,
            nullptr, nullptr, nullptr,
            x1Buf, statsBase(l, 0), N);
        gemm_kernel<1><<<gemmGrid, 256, 0, stream>>>(
            x1Buf, WtHi + (5 + l) * 16384, WtLo + (5 + l) * 16384, b2 + l * 128,
            statsBase(l, 0), bn1g + l * 128, bn1b + l * 128,
            x2Buf, statsBase(l, 1), N);
        elt_kernel<<<256, 256, 0, stream>>>(
            x2Buf, statsBase(l, 1), bn2g + l * 128, bn2b + l * 128,
            statsBase(l, 2), N);
    }
    final_kernel<<<512, 256, 0, stream>>>(
        buf0,
        statsBase(4, 1), bn2g + 4 * 128, bn2b + 4 * 128,
        statsBase(4, 2), bn3g + 4 * 128, bn3b + 4 * 128,
        (float*)d_out, N);
}

// Round 6
// 655.194 us; speedup vs baseline: 1.1480x; 1.1480x over previous
//
#include <hip/hip_runtime.h>
#include <hip/hip_bf16.h>
#include <cstdint>

#define BN_EPS 1e-5f

typedef __attribute__((ext_vector_type(8))) short short8;
typedef __attribute__((ext_vector_type(8))) __bf16 bf16x8;
typedef __attribute__((ext_vector_type(4))) float f32x4;

__device__ inline short f2bf(float f) {
    union { float f; unsigned u; } v; v.f = f;
    unsigned r = v.u + 0x7fffu + ((v.u >> 16) & 1u); // RNE
    return (short)(r >> 16);
}
__device__ inline float bf2f(short h) {
    union { unsigned u; float f; } v;
    v.u = ((unsigned)(unsigned short)h) << 16;
    return v.f;
}

// ---------------- setup kernels ----------------

__global__ void zero_kernel(float* stats, int nstats, int* deg, int N) {
    int i = blockIdx.x * 256 + threadIdx.x;
    if (i < nstats) stats[i] = 0.f;
    if (i < N) deg[i] = 0;
}

// h0 f32 -> bf16
__global__ void h2bf_kernel(const float* __restrict__ h, unsigned short* __restrict__ hb,
                            int total4) {
    int i = blockIdx.x * 256 + threadIdx.x;
    if (i >= total4) return;
    float4 v = ((const float4*)h)[i];
    ushort4 o;
    o.x = (unsigned short)f2bf(v.x);
    o.y = (unsigned short)f2bf(v.y);
    o.z = (unsigned short)f2bf(v.z);
    o.w = (unsigned short)f2bf(v.w);
    ((ushort4*)hb)[i] = o;
}

// transpose + bf16 split weights: WtHi/WtLo[mat][n][k] = split(W[mat][k][n])
__global__ void tw_kernel(const float* __restrict__ W1, const float* __restrict__ W2,
                          short* __restrict__ WtHi, short* __restrict__ WtLo) {
    int t = blockIdx.x * 256 + threadIdx.x;
    if (t >= 10 * 128 * 128) return;
    int mat = t >> 14, n = (t >> 7) & 127, k = t & 127;
    const float* W = (mat < 5) ? (W1 + mat * 16384) : (W2 + (mat - 5) * 16384);
    float w = W[k * 128 + n];
    short hi = f2bf(w);
    WtHi[t] = hi;
    WtLo[t] = f2bf(w - bf2f(hi));
}

__global__ void count_kernel(const int* __restrict__ dst, int* __restrict__ deg, int E) {
    int e = blockIdx.x * 256 + threadIdx.x;
    if (e < E) atomicAdd(&deg[dst[e]], 1);
}

// ---- multi-block exclusive scan of deg -> rowptr/cursor ----

__global__ __launch_bounds__(256) void scanA_kernel(const int* __restrict__ deg,
                                                    int* __restrict__ blockSums, int N) {
    int t = threadIdx.x, b = blockIdx.x;
    int base = b * 1024 + t * 4;
    int s = 0;
#pragma unroll
    for (int k = 0; k < 4; ++k) { int i = base + k; if (i < N) s += deg[i]; }
#pragma unroll
    for (int off = 1; off < 64; off <<= 1) s += __shfl_xor(s, off, 64);
    __shared__ int ws[4];
    if ((t & 63) == 0) ws[t >> 6] = s;
    __syncthreads();
    if (t == 0) blockSums[b] = ws[0] + ws[1] + ws[2] + ws[3];
}

__global__ __launch_bounds__(256) void scanB_kernel(int* __restrict__ blockSums,
                                                    int* __restrict__ rowptrN, int nb) {
    __shared__ int ps[256];
    int t = threadIdx.x;
    int v = (t < nb) ? blockSums[t] : 0;
    ps[t] = v;
    __syncthreads();
#pragma unroll
    for (int off = 1; off < 256; off <<= 1) {
        int u = 0;
        if (t >= off) u = ps[t - off];
        __syncthreads();
        ps[t] += u;
        __syncthreads();
    }
    if (t < nb) blockSums[t] = ps[t] - v;
    if (t == 255) rowptrN[0] = ps[255];
}

__global__ __launch_bounds__(256) void scanC_kernel(const int* __restrict__ deg,
                                                    const int* __restrict__ blockSums,
                                                    int* __restrict__ rowptr,
                                                    int* __restrict__ cursor, int N) {
    __shared__ int ps[256];
    int t = threadIdx.x, b = blockIdx.x;
    int base = b * 1024 + t * 4;
    int d[4];
    int s = 0;
#pragma unroll
    for (int k = 0; k < 4; ++k) {
        d[k] = (base + k < N) ? deg[base + k] : 0;
        s += d[k];
    }
    int local = s;
    ps[t] = s;
    __syncthreads();
#pragma unroll
    for (int off = 1; off < 256; off <<= 1) {
        int u = 0;
        if (t >= off) u = ps[t - off];
        __syncthreads();
        ps[t] += u;
        __syncthreads();
    }
    int pre = ps[t] - local + blockSums[b];
#pragma unroll
    for (int k = 0; k < 4; ++k) {
        int i = base + k;
        if (i < N) { rowptr[i] = pre; cursor[i] = pre; pre += d[k]; }
    }
}

__global__ void fill_kernel(const int* __restrict__ src, const int* __restrict__ dst,
                            int* __restrict__ cursor, int* __restrict__ colidx, int E) {
    int e = blockIdx.x * 256 + threadIdx.x;
    if (e < E) {
        int p = atomicAdd(&cursor[dst[e]], 1);
        colidx[p] = src[e];
    }
}

// coeff from striped stats [8][256]: a = g*rsqrt(var+eps), c = b - mean*a
__device__ inline void coeff_from_stats(const float* __restrict__ stats,
                                        const float* __restrict__ g,
                                        const float* __restrict__ bb,
                                        int col, int N, float& a, float& c) {
    float s = 0.f, q = 0.f;
#pragma unroll
    for (int st = 0; st < 8; ++st) {
        s += stats[st * 256 + col];
        q += stats[st * 256 + 128 + col];
    }
    float m = s / N, v = q / N - m * m;
    a = g[col] * rsqrtf(v + BN_EPS);
    c = bb[col] - m * a;
}

// ---------------- aggregation: rst[i] = f(x[i]) + sum_{j in in(i)} f(x[j]) ----------------
// X is bf16. MODE 0: f = identity. MODE 1: f(u) = relu(a3*relu(a2*u+c2)+c3), coeffs inline.
// One wave per node; lane covers cols 2*lane, 2*lane+1 (ushort2 load). Edge unroll x8.

template <int MODE>
__global__ __launch_bounds__(256) void agg_kernel(
    const unsigned short* __restrict__ Xb, const int* __restrict__ rowptr,
    const int* __restrict__ colidx,
    const float* __restrict__ stats2, const float* __restrict__ g2, const float* __restrict__ b2v,
    const float* __restrict__ stats3, const float* __restrict__ g3, const float* __restrict__ b3v,
    float* __restrict__ rst, int N) {
    __shared__ float cf[4][128];
    int t = threadIdx.x;
    if (MODE) {
        if (t < 128) {
            float a, c;
            coeff_from_stats(stats2, g2, b2v, t, N, a, c);
            cf[0][t] = a; cf[1][t] = c;
            coeff_from_stats(stats3, g3, b3v, t, N, a, c);
            cf[2][t] = a; cf[3][t] = c;
        }
        __syncthreads();
    }
    int node = (blockIdx.x * 256 + t) >> 6;
    if (node >= N) return;
    int lane = t & 63;
    int c0 = lane * 2, c1 = c0 + 1;
    float a2x = 1.f, c2x = 0.f, a2y = 1.f, c2y = 0.f;
    float a3x = 1.f, c3x = 0.f, a3y = 1.f, c3y = 0.f;
    if (MODE) {
        a2x = cf[0][c0]; a2y = cf[0][c1]; c2x = cf[1][c0]; c2y = cf[1][c1];
        a3x = cf[2][c0]; a3y = cf[2][c1]; c3x = cf[3][c0]; c3y = cf[3][c1];
    }
    auto fx = [&](float u) {
        if (MODE == 0) return u;
        float z = fmaxf(a2x * u + c2x, 0.f);
        return fmaxf(a3x * z + c3x, 0.f);
    };
    auto fy = [&](float u) {
        if (MODE == 0) return u;
        float z = fmaxf(a2y * u + c2y, 0.f);
        return fmaxf(a3y * z + c3y, 0.f);
    };
    const ushort2* X2 = (const ushort2*)Xb;
    ushort2 self = X2[(size_t)node * 64 + lane];
    float ax = fx(bf2f((short)self.x)), ay = fy(bf2f((short)self.y));
    int e = rowptr[node], end = rowptr[node + 1];
    for (; e + 8 <= end; e += 8) {
        int j[8];
#pragma unroll
        for (int k = 0; k < 8; ++k) j[k] = colidx[e + k];
        ushort2 v[8];
#pragma unroll
        for (int k = 0; k < 8; ++k) v[k] = X2[(size_t)j[k] * 64 + lane];
#pragma unroll
        for (int k = 0; k < 8; ++k) {
            ax += fx(bf2f((short)v[k].x));
            ay += fy(bf2f((short)v[k].y));
        }
    }
    for (; e < end; ++e) {
        int j = colidx[e];
        ushort2 v = X2[(size_t)j * 64 + lane];
        ax += fx(bf2f((short)v.x));
        ay += fy(bf2f((short)v.y));
    }
    float2 r; r.x = ax; r.y = ay;
    ((float2*)rst)[(size_t)node * 64 + lane] = r;
}

// ---------------- GEMM: C = pre(A) @ W + bias, striped column stats ----------------
// W hi/lo staged in LDS (XOR-swizzled); A (f32) streamed global->registers, split bf16.
// PRE==1: relu(a*x+c), coeffs per-lane from striped stats redistributed via __shfl.
// OUTBF==1: write C as bf16 (ushort), stats on the rounded values.

template <int PRE, int OUTBF>
__global__ __launch_bounds__(256, 2) void gemm_kernel(
    const float* __restrict__ A,
    const short* __restrict__ WtHi, const short* __restrict__ WtLo,
    const float* __restrict__ bias,
    const float* __restrict__ preStats, const float* __restrict__ preG,
    const float* __restrict__ preB,
    float* __restrict__ C, unsigned short* __restrict__ Cb,
    float* __restrict__ outStats, int N) {
    __shared__ short WsHi[128 * 128];
    __shared__ short WsLo[128 * 128];

    const int t = threadIdx.x;
    const int row0 = blockIdx.x * 128;
    const int w = t >> 6, lane = t & 63;
    const int quad = lane >> 4, l16 = lane & 15;
    const int sw = (l16 & 7) * 8;

    float aE = 1.f, cE = 0.f, aO = 1.f, cO = 0.f;
    if (PRE) {
        coeff_from_stats(preStats, preG, preB, lane * 2, N, aE, cE);
        coeff_from_stats(preStats, preG, preB, lane * 2 + 1, N, aO, cO);
    }

    // phase 1: A f32 loads (rows w*32+l16, w*32+16+l16)
    float4 af[2][4][2];
#pragma unroll
    for (int m = 0; m < 2; ++m) {
        int gr = row0 + w * 32 + m * 16 + l16;
        bool ok = gr < N;
        const float* Ar = A + (size_t)gr * 128;
#pragma unroll
        for (int kk = 0; kk < 4; ++kk) {
            int kb = kk * 32 + quad * 8;
            af[m][kk][0] = ok ? *(const float4*)(Ar + kb) : make_float4(0.f, 0.f, 0.f, 0.f);
            af[m][kk][1] = ok ? *(const float4*)(Ar + kb + 4) : make_float4(0.f, 0.f, 0.f, 0.f);
        }
    }

    // phase 2: stage W hi/lo into LDS, XOR-swizzled rows
#pragma unroll
    for (int i = 0; i < 8; ++i) {
        int ch = t + i * 256;
        int r = ch >> 4, k = (ch & 15) * 8;
        int d = r * 128 + (k ^ ((r & 7) * 8));
        *(short8*)(WsHi + d) = *(const short8*)(WtHi + r * 128 + k);
        *(short8*)(WsLo + d) = *(const short8*)(WtLo + r * 128 + k);
    }
    __syncthreads();

    // phase 3: BN + split-convert A fragments (coeffs via shuffle)
    short8 fh[2][4], fl[2][4];
#pragma unroll
    for (int kk = 0; kk < 4; ++kk) {
        float a8[8], c8[8];
#pragma unroll
        for (int j = 0; j < 8; ++j) {
            if (PRE) {
                int col = kk * 32 + quad * 8 + j;
                int srcl = col >> 1;
                a8[j] = __shfl((j & 1) ? aO : aE, srcl, 64);
                c8[j] = __shfl((j & 1) ? cO : cE, srcl, 64);
            }
        }
#pragma unroll
        for (int m = 0; m < 2; ++m) {
            float x[8];
            *(float4*)(x) = af[m][kk][0];
            *(float4*)(x + 4) = af[m][kk][1];
            short8 h, lo;
#pragma unroll
            for (int j = 0; j < 8; ++j) {
                float y = PRE ? fmaxf(a8[j] * x[j] + c8[j], 0.f) : x[j];
                short hi = f2bf(y);
                h[j] = hi;
                lo[j] = f2bf(y - bf2f(hi));
            }
            fh[m][kk] = h;
            fl[m][kk] = lo;
        }
    }

    f32x4 acc[2][8];
#pragma unroll
    for (int m = 0; m < 2; ++m)
#pragma unroll
        for (int n = 0; n < 8; ++n) acc[m][n] = (f32x4){0.f, 0.f, 0.f, 0.f};

#pragma unroll
    for (int kk = 0; kk < 4; ++kk) {
        int kb = kk * 32 + quad * 8;
        bf16x8 a0h = __builtin_bit_cast(bf16x8, fh[0][kk]);
        bf16x8 a1h = __builtin_bit_cast(bf16x8, fh[1][kk]);
        bf16x8 a0l = __builtin_bit_cast(bf16x8, fl[0][kk]);
        bf16x8 a1l = __builtin_bit_cast(bf16x8, fl[1][kk]);
#pragma unroll
        for (int n = 0; n < 8; ++n) {
            int woff = (n * 16 + l16) * 128 + (kb ^ sw);
            bf16x8 bh = __builtin_bit_cast(bf16x8, *(const short8*)(WsHi + woff));
            bf16x8 bl = __builtin_bit_cast(bf16x8, *(const short8*)(WsLo + woff));
            acc[0][n] = __builtin_amdgcn_mfma_f32_16x16x32_bf16(a0h, bh, acc[0][n], 0, 0, 0);
            acc[0][n] = __builtin_amdgcn_mfma_f32_16x16x32_bf16(a0l, bh, acc[0][n], 0, 0, 0);
            acc[0][n] = __builtin_amdgcn_mfma_f32_16x16x32_bf16(a0h, bl, acc[0][n], 0, 0, 0);
            acc[1][n] = __builtin_amdgcn_mfma_f32_16x16x32_bf16(a1h, bh, acc[1][n], 0, 0, 0);
            acc[1][n] = __builtin_amdgcn_mfma_f32_16x16x32_bf16(a1l, bh, acc[1][n], 0, 0, 0);
            acc[1][n] = __builtin_amdgcn_mfma_f32_16x16x32_bf16(a1h, bl, acc[1][n], 0, 0, 0);
        }
    }

    __syncthreads(); // all LDS reads done; WsHi reused below for stats reduction

    float bv[8];
#pragma unroll
    for (int n = 0; n < 8; ++n) bv[n] = bias[n * 16 + l16];
    float ls[8], lsq[8];
#pragma unroll
    for (int n = 0; n < 8; ++n) { ls[n] = 0.f; lsq[n] = 0.f; }
#pragma unroll
    for (int m = 0; m < 2; ++m) {
        int rbase = row0 + w * 32 + m * 16 + quad * 4;
#pragma unroll
        for (int n = 0; n < 8; ++n) {
            int colv = n * 16 + l16;
#pragma unroll
            for (int r = 0; r < 4; ++r) {
                int row = rbase + r;
                if (row < N) {
                    float val = acc[m][n][r] + bv[n];
                    if (OUTBF) {
                        short hb = f2bf(val);
                        float vr = bf2f(hb);
                        Cb[(size_t)row * 128 + colv] = (unsigned short)hb;
                        ls[n] += vr;
                        lsq[n] += vr * vr;
                    } else {
                        C[(size_t)row * 128 + colv] = val;
                        ls[n] += val;
                        lsq[n] += val * val;
                    }
                }
            }
        }
    }

    float* P = (float*)WsHi;
#pragma unroll
    for (int n = 0; n < 8; ++n) {
        float s = ls[n], q = lsq[n];
        s += __shfl_xor(s, 16, 64);
        s += __shfl_xor(s, 32, 64);
        q += __shfl_xor(q, 16, 64);
        q += __shfl_xor(q, 32, 64);
        if (quad == 0) {
            int colv = n * 16 + l16;
            P[w * 512 + colv] = s;
            P[w * 512 + 256 + colv] = q;
        }
    }
    __syncthreads();

    int stripe = blockIdx.x & 7;
    if (t < 128) {
        int col = t;
        float S = P[col] + P[512 + col] + P[1024 + col] + P[1536 + col];
        atomicAdd(&outStats[stripe * 256 + col], S);
    } else {
        int col = t - 128;
        float Q = P[256 + col] + P[768 + col] + P[1280 + col] + P[1792 + col];
        atomicAdd(&outStats[stripe * 256 + 128 + col], Q);
    }
}

// ---------------- stats of y = relu(a*x+c) over bf16 X (no materialization) ----------------

__global__ __launch_bounds__(256) void elt_kernel(
    const unsigned short* __restrict__ Xb,
    const float* __restrict__ inStats, const float* __restrict__ g, const float* __restrict__ bb,
    float* __restrict__ outStats, int N) {
    __shared__ float red[256 * 8];
    __shared__ float cf[2][128];
    int t = threadIdx.x;
    if (t < 128) {
        float a, c;
        coeff_from_stats(inStats, g, bb, t, N, a, c);
        cf[0][t] = a; cf[1][t] = c;
    }
    __syncthreads();
    int cg = t & 31;
    float a[4], c[4];
#pragma unroll
    for (int k = 0; k < 4; ++k) {
        a[k] = cf[0][cg * 4 + k];
        c[k] = cf[1][cg * 4 + k];
    }
    float sum[4] = {0.f, 0.f, 0.f, 0.f}, sq[4] = {0.f, 0.f, 0.f, 0.f};
    int total = N * 32;
    for (int i = blockIdx.x * 256 + t; i < total; i += gridDim.x * 256) {
        ushort4 u = ((const ushort4*)Xb)[i];
        float y0 = fmaxf(a[0] * bf2f((short)u.x) + c[0], 0.f);
        float y1 = fmaxf(a[1] * bf2f((short)u.y) + c[1], 0.f);
        float y2 = fmaxf(a[2] * bf2f((short)u.z) + c[2], 0.f);
        float y3 = fmaxf(a[3] * bf2f((short)u.w) + c[3], 0.f);
        sum[0] += y0; sq[0] += y0 * y0;
        sum[1] += y1; sq[1] += y1 * y1;
        sum[2] += y2; sq[2] += y2 * y2;
        sum[3] += y3; sq[3] += y3 * y3;
    }
#pragma unroll
    for (int k = 0; k < 4; ++k) { red[t * 8 + k] = sum[k]; red[t * 8 + 4 + k] = sq[k]; }
    __syncthreads();
    if (t < 32) {
        float S[4] = {0.f, 0.f, 0.f, 0.f}, Q[4] = {0.f, 0.f, 0.f, 0.f};
        for (int j = 0; j < 8; ++j) {
            int tt = t + 32 * j;
#pragma unroll
            for (int k = 0; k < 4; ++k) { S[k] += red[tt * 8 + k]; Q[k] += red[tt * 8 + 4 + k]; }
        }
        int stripe = blockIdx.x & 7;
#pragma unroll
        for (int k = 0; k < 4; ++k) {
            atomicAdd(&outStats[stripe * 256 + t * 4 + k], S[k]);
            atomicAdd(&outStats[stripe * 256 + 128 + t * 4 + k], Q[k]);
        }
    }
}

// ---------------- final: out = relu(a3*relu(a2*x+c2)+c3) from bf16 X ----------------

__global__ __launch_bounds__(256) void final_kernel(
    const unsigned short* __restrict__ Xb,
    const float* __restrict__ stats2, const float* __restrict__ g2, const float* __restrict__ b2v,
    const float* __restrict__ stats3, const float* __restrict__ g3, const float* __restrict__ b3v,
    float* __restrict__ out, int N) {
    __shared__ float cf[4][128];
    int t = threadIdx.x;
    if (t < 128) {
        float a, c;
        coeff_from_stats(stats2, g2, b2v, t, N, a, c);
        cf[0][t] = a; cf[1][t] = c;
        coeff_from_stats(stats3, g3, b3v, t, N, a, c);
        cf[2][t] = a; cf[3][t] = c;
    }
    __syncthreads();
    int cg = t & 31;
    float a2[4], c2[4], a3[4], c3[4];
#pragma unroll
    for (int k = 0; k < 4; ++k) {
        int colv = cg * 4 + k;
        a2[k] = cf[0][colv]; c2[k] = cf[1][colv];
        a3[k] = cf[2][colv]; c3[k] = cf[3][colv];
    }
    int total = N * 32;
    for (int i = blockIdx.x * 256 + t; i < total; i += gridDim.x * 256) {
        ushort4 u = ((const ushort4*)Xb)[i];
        float4 y;
        y.x = fmaxf(a3[0] * fmaxf(a2[0] * bf2f((short)u.x) + c2[0], 0.f) + c3[0], 0.f);
        y.y = fmaxf(a3[1] * fmaxf(a2[1] * bf2f((short)u.y) + c2[1], 0.f) + c3[1], 0.f);
        y.z = fmaxf(a3[2] * fmaxf(a2[2] * bf2f((short)u.z) + c2[2], 0.f) + c3[2], 0.f);
        y.w = fmaxf(a3[3] * fmaxf(a2[3] * bf2f((short)u.w) + c2[3], 0.f) + c3[3], 0.f);
        ((float4*)out)[i] = y;
    }
}

// ---------------- launch ----------------

extern "C" void kernel_launch(void* const* d_in, const int* in_sizes, int n_in,
                              void* d_out, int out_size, void* d_ws, size_t ws_size,
                              hipStream_t stream) {
    const float* h0   = (const float*)d_in[0];
    const int*   src  = (const int*)d_in[1];
    const int*   dst  = (const int*)d_in[2];
    const float* W1   = (const float*)d_in[3];
    const float* b1   = (const float*)d_in[4];
    const float* W2   = (const float*)d_in[5];
    const float* b2   = (const float*)d_in[6];
    const float* bn1g = (const float*)d_in[7];
    const float* bn1b = (const float*)d_in[8];
    const float* bn2g = (const float*)d_in[9];
    const float* bn2b = (const float*)d_in[10];
    const float* bn3g = (const float*)d_in[11];
    const float* bn3b = (const float*)d_in[12];
    const int N = in_sizes[0] / 128;
    const int E = in_sizes[1];

    char* ws = (char*)d_ws;
    size_t off = 0;
    auto alloc = [&](size_t bytes) {
        void* p = ws + off;
        off = (off + bytes + 255) & ~(size_t)255;
        return p;
    };
    float* stats   = (float*)alloc((size_t)5 * 3 * 8 * 256 * sizeof(float)); // striped
    int*   deg     = (int*)alloc((size_t)N * 4);
    int*   cursor  = (int*)alloc((size_t)N * 4);
    int*   rowptr  = (int*)alloc((size_t)(N + 1) * 4);
    int*   colidx  = (int*)alloc((size_t)E * 4);
    int*   bsums   = (int*)alloc(1024);
    short* WtHi    = (short*)alloc((size_t)10 * 16384 * 2);
    short* WtLo    = (short*)alloc((size_t)10 * 16384 * 2);
    float* buf0    = (float*)alloc((size_t)N * 128 * 4);       // rst (f32)
    float* buf1    = (float*)alloc((size_t)N * 128 * 4);       // x1 (f32)
    unsigned short* xbf = (unsigned short*)alloc((size_t)N * 128 * 2); // h0/x2 (bf16)

    auto statsBase = [&](int l, int which) { return stats + ((size_t)(l * 3 + which)) * 8 * 256; };

    const int nstats = 5 * 3 * 8 * 256;
    int zgrid = ((N > nstats ? N : nstats) + 255) / 256;
    zero_kernel<<<zgrid, 256, 0, stream>>>(stats, nstats, deg, N);
    h2bf_kernel<<<(N * 32 + 255) / 256, 256, 0, stream>>>(h0, xbf, N * 32);
    tw_kernel<<<(10 * 16384 + 255) / 256, 256, 0, stream>>>(W1, W2, WtHi, WtLo);
    count_kernel<<<(E + 255) / 256, 256, 0, stream>>>(dst, deg, E);
    int nb = (N + 1023) / 1024;
    scanA_kernel<<<nb, 256, 0, stream>>>(deg, bsums, N);
    scanB_kernel<<<1, 256, 0, stream>>>(bsums, rowptr + N, nb);
    scanC_kernel<<<nb, 256, 0, stream>>>(deg, bsums, rowptr, cursor, N);
    fill_kernel<<<(E + 255) / 256, 256, 0, stream>>>(src, dst, cursor, colidx, E);

    const int gemmGrid = (N + 127) / 128;
    const int aggGrid = (N + 3) / 4;
    for (int l = 0; l < 5; ++l) {
        if (l == 0) {
            agg_kernel<0><<<aggGrid, 256, 0, stream>>>(
                xbf, rowptr, colidx,
                nullptr, nullptr, nullptr, nullptr, nullptr, nullptr,
                buf0, N);
        } else {
            int lp = l - 1;
            agg_kernel<1><<<aggGrid, 256, 0, stream>>>(
                xbf, rowptr, colidx,
                statsBase(lp, 1), bn2g + lp * 128, bn2b + lp * 128,
                statsBase(lp, 2), bn3g + lp * 128, bn3b + lp * 128,
                buf0, N);
        }
        gemm_kernel<0, 0><<<gemmGrid, 256, 0, stream>>>(
            buf0, WtHi + l * 16384, WtLo + l * 16384, b1 + l * 128,
            nullptr, nullptr, nullptr,
            buf1, nullptr, statsBase(l, 0), N);
        gemm_kernel<1, 1><<<gemmGrid, 256, 0, stream>>>(
            buf1, WtHi + (5 + l) * 16384, WtLo + (5 + l) * 16384, b2 + l * 128,
            statsBase(l, 0), bn1g + l * 128, bn1b + l * 128,
            nullptr, xbf, statsBase(l, 1), N);
        elt_kernel<<<256, 256, 0, stream>>>(
            xbf, statsBase(l, 1), bn2g + l * 128, bn2b + l * 128,
            statsBase(l, 2), N);
    }
    final_kernel<<<512, 256, 0, stream>>>(
        xbf,
        statsBase(4, 1), bn2g + 4 * 128, bn2b + 4 * 128,
        statsBase(4, 2), bn3g + 4 * 128, bn3b + 4 * 128,
        (float*)d_out, N);
}

// Round 7
// 585.368 us; speedup vs baseline: 1.2849x; 1.1193x over previous
//
#include <hip/hip_runtime.h>
#include <hip/hip_bf16.h>
#include <cstdint>

#define BN_EPS 1e-5f
#define CSR_SHIFT 7
#define NBMAX 512

typedef __attribute__((ext_vector_type(8))) short short8;
typedef __attribute__((ext_vector_type(8))) __bf16 bf16x8;
typedef __attribute__((ext_vector_type(4))) float f32x4;

__device__ inline short f2bf(float f) {
    union { float f; unsigned u; } v; v.f = f;
    unsigned r = v.u + 0x7fffu + ((v.u >> 16) & 1u); // RNE
    return (short)(r >> 16);
}
__device__ inline float bf2f(short h) {
    union { unsigned u; float f; } v;
    v.u = ((unsigned)(unsigned short)h) << 16;
    return v.f;
}
__device__ inline unsigned asu(float f) { union { float f; unsigned u; } v; v.f = f; return v.u; }
__device__ inline float asf(unsigned u) { union { unsigned u; float f; } v; v.u = u; return v.f; }

// ---------------- setup kernels ----------------

__global__ void zero_kernel(float* stats, int nstats, int* bcnt, int nb) {
    int i = blockIdx.x * 256 + threadIdx.x;
    if (i < nstats) stats[i] = 0.f;
    if (i < nb) bcnt[i] = 0;
}

// h0 f32 -> bf16
__global__ void h2bf_kernel(const float* __restrict__ h, unsigned short* __restrict__ hb,
                            int total4) {
    int i = blockIdx.x * 256 + threadIdx.x;
    if (i >= total4) return;
    float4 v = ((const float4*)h)[i];
    ushort4 o;
    o.x = (unsigned short)f2bf(v.x);
    o.y = (unsigned short)f2bf(v.y);
    o.z = (unsigned short)f2bf(v.z);
    o.w = (unsigned short)f2bf(v.w);
    ((ushort4*)hb)[i] = o;
}

// transpose + bf16 split weights: WtHi/WtLo[mat][n][k] = split(W[mat][k][n])
__global__ void tw_kernel(const float* __restrict__ W1, const float* __restrict__ W2,
                          short* __restrict__ WtHi, short* __restrict__ WtLo) {
    int t = blockIdx.x * 256 + threadIdx.x;
    if (t >= 10 * 128 * 128) return;
    int mat = t >> 14, n = (t >> 7) & 127, k = t & 127;
    const float* W = (mat < 5) ? (W1 + mat * 16384) : (W2 + (mat - 5) * 16384);
    float w = W[k * 128 + n];
    short hi = f2bf(w);
    WtHi[t] = hi;
    WtLo[t] = f2bf(w - bf2f(hi));
}

// ---- bucketed CSR build: bucket = dst >> 7 (128 nodes/bucket) ----

__global__ __launch_bounds__(256) void bcount_kernel(const int* __restrict__ dst,
                                                     int* __restrict__ bucketCnt,
                                                     int E, int nb, int chunk) {
    __shared__ int hist[NBMAX];
    int t = threadIdx.x;
    for (int i = t; i < nb; i += 256) hist[i] = 0;
    __syncthreads();
    int s = blockIdx.x * chunk, e = s + chunk; if (e > E) e = E;
    for (int i = s + t; i < e; i += 256) atomicAdd(&hist[dst[i] >> CSR_SHIFT], 1);
    __syncthreads();
    for (int i = t; i < nb; i += 256) if (hist[i]) atomicAdd(&bucketCnt[i], hist[i]);
}

__global__ __launch_bounds__(512) void bscan_kernel(const int* __restrict__ bucketCnt,
                                                    int* __restrict__ bucketBase,
                                                    int* __restrict__ bucketCursor,
                                                    int* __restrict__ rowptr,
                                                    int nb, int N, int E) {
    __shared__ int ps[NBMAX];
    int t = threadIdx.x;
    int v = (t < nb) ? bucketCnt[t] : 0;
    ps[t] = v;
    __syncthreads();
#pragma unroll
    for (int off = 1; off < NBMAX; off <<= 1) {
        int u = 0;
        if (t >= off) u = ps[t - off];
        __syncthreads();
        ps[t] += u;
        __syncthreads();
    }
    if (t < nb) {
        int b = ps[t] - v; // exclusive
        bucketBase[t] = b;
        bucketCursor[t] = b;
    }
    if (t == 0) { bucketBase[nb] = E; rowptr[N] = E; }
}

// block-aggregated scatter of (src,dst) pairs into bucket regions
__global__ __launch_bounds__(256) void bscatter_kernel(const int* __restrict__ src,
                                                       const int* __restrict__ dst,
                                                       int* __restrict__ bucketCursor,
                                                       uint2* __restrict__ pairs,
                                                       int E, int nb, int chunk) {
    __shared__ int cnt[NBMAX];
    __shared__ int base[NBMAX];
    int t = threadIdx.x;
    for (int i = t; i < nb; i += 256) cnt[i] = 0;
    __syncthreads();
    int s = blockIdx.x * chunk, e = s + chunk; if (e > E) e = E;
    for (int i = s + t; i < e; i += 256) atomicAdd(&cnt[dst[i] >> CSR_SHIFT], 1);
    __syncthreads();
    for (int i = t; i < nb; i += 256) {
        int c = cnt[i];
        base[i] = c ? atomicAdd(&bucketCursor[i], c) : 0;
    }
    __syncthreads();
    for (int i = t; i < nb; i += 256) cnt[i] = 0;
    __syncthreads();
    for (int i = s + t; i < e; i += 256) {
        int d = dst[i];
        int b = d >> CSR_SHIFT;
        int slot = atomicAdd(&cnt[b], 1);
        pairs[base[b] + slot] = make_uint2((unsigned)src[i], (unsigned)d);
    }
}

// per-bucket: node counts -> rowptr, scatter src into contiguous colidx
__global__ __launch_bounds__(256) void bbuild_kernel(const uint2* __restrict__ pairs,
                                                     const int* __restrict__ bucketBase,
                                                     int* __restrict__ rowptr,
                                                     int* __restrict__ colidx, int N) {
    __shared__ int cnt[128];
    int b = blockIdx.x, t = threadIdx.x;
    int lo = bucketBase[b], hi = bucketBase[b + 1];
    if (t < 128) cnt[t] = 0;
    __syncthreads();
    for (int e = lo + t; e < hi; e += 256) atomicAdd(&cnt[pairs[e].y & 127], 1);
    __syncthreads();
    int orig = (t < 128) ? cnt[t] : 0;
#pragma unroll
    for (int o = 1; o < 128; o <<= 1) {
        int u = 0;
        if (t < 128 && t >= o) u = cnt[t - o];
        __syncthreads();
        if (t < 128) cnt[t] += u;
        __syncthreads();
    }
    int ex = (t < 128) ? (cnt[t] - orig) : 0;
    if (t < 128) {
        int node = b * 128 + t;
        if (node < N) rowptr[node] = lo + ex;
    }
    __syncthreads();
    if (t < 128) cnt[t] = ex; // reuse as cursor
    __syncthreads();
    for (int e = lo + t; e < hi; e += 256) {
        uint2 p = pairs[e];
        int slot = atomicAdd(&cnt[p.y & 127], 1);
        colidx[lo + slot] = (int)p.x;
    }
}

// coeff from striped stats [8][256]: a = g*rsqrt(var+eps), c = b - mean*a
__device__ inline void coeff_from_stats(const float* __restrict__ stats,
                                        const float* __restrict__ g,
                                        const float* __restrict__ bb,
                                        int col, int N, float& a, float& c) {
    float s = 0.f, q = 0.f;
#pragma unroll
    for (int st = 0; st < 8; ++st) {
        s += stats[st * 256 + col];
        q += stats[st * 256 + 128 + col];
    }
    float m = s / N, v = q / N - m * m;
    a = g[col] * rsqrtf(v + BN_EPS);
    c = bb[col] - m * a;
}

// ---------------- aggregation: rst[i] = f(x[i]) + sum_{j in in(i)} f(x[j]) ----------------
// X is bf16. MODE 0: f = identity. MODE 1: f(u) = relu(a3*relu(a2*u+c2)+c3), coeffs inline.
// One wave per node; lane covers cols 2*lane, 2*lane+1. Edge unroll 16/4/1.

template <int MODE>
__global__ __launch_bounds__(256) void agg_kernel(
    const unsigned short* __restrict__ Xb, const int* __restrict__ rowptr,
    const int* __restrict__ colidx,
    const float* __restrict__ stats2, const float* __restrict__ g2, const float* __restrict__ b2v,
    const float* __restrict__ stats3, const float* __restrict__ g3, const float* __restrict__ b3v,
    float* __restrict__ rst, int N) {
    __shared__ float cf[4][128];
    int t = threadIdx.x;
    if (MODE) {
        if (t < 128) {
            float a, c;
            coeff_from_stats(stats2, g2, b2v, t, N, a, c);
            cf[0][t] = a; cf[1][t] = c;
            coeff_from_stats(stats3, g3, b3v, t, N, a, c);
            cf[2][t] = a; cf[3][t] = c;
        }
        __syncthreads();
    }
    int node = (blockIdx.x * 256 + t) >> 6;
    if (node >= N) return;
    int lane = t & 63;
    int c0 = lane * 2, c1 = c0 + 1;
    float a2x = 1.f, c2x = 0.f, a2y = 1.f, c2y = 0.f;
    float a3x = 1.f, c3x = 0.f, a3y = 1.f, c3y = 0.f;
    if (MODE) {
        a2x = cf[0][c0]; a2y = cf[0][c1]; c2x = cf[1][c0]; c2y = cf[1][c1];
        a3x = cf[2][c0]; a3y = cf[2][c1]; c3x = cf[3][c0]; c3y = cf[3][c1];
    }
    auto fx = [&](float u) {
        if (MODE == 0) return u;
        float z = fmaxf(a2x * u + c2x, 0.f);
        return fmaxf(a3x * z + c3x, 0.f);
    };
    auto fy = [&](float u) {
        if (MODE == 0) return u;
        float z = fmaxf(a2y * u + c2y, 0.f);
        return fmaxf(a3y * z + c3y, 0.f);
    };
    const ushort2* X2 = (const ushort2*)Xb;
    ushort2 self = X2[(size_t)node * 64 + lane];
    float ax = fx(bf2f((short)self.x)), ay = fy(bf2f((short)self.y));
    int e = rowptr[node], end = rowptr[node + 1];
    for (; e + 16 <= end; e += 16) {
        int j[16];
#pragma unroll
        for (int k = 0; k < 16; ++k) j[k] = colidx[e + k];
        ushort2 v[16];
#pragma unroll
        for (int k = 0; k < 16; ++k) v[k] = X2[(size_t)j[k] * 64 + lane];
#pragma unroll
        for (int k = 0; k < 16; ++k) {
            ax += fx(bf2f((short)v[k].x));
            ay += fy(bf2f((short)v[k].y));
        }
    }
    for (; e + 4 <= end; e += 4) {
        int j[4];
#pragma unroll
        for (int k = 0; k < 4; ++k) j[k] = colidx[e + k];
        ushort2 v[4];
#pragma unroll
        for (int k = 0; k < 4; ++k) v[k] = X2[(size_t)j[k] * 64 + lane];
#pragma unroll
        for (int k = 0; k < 4; ++k) {
            ax += fx(bf2f((short)v[k].x));
            ay += fy(bf2f((short)v[k].y));
        }
    }
    for (; e < end; ++e) {
        int j = colidx[e];
        ushort2 v = X2[(size_t)j * 64 + lane];
        ax += fx(bf2f((short)v.x));
        ay += fy(bf2f((short)v.y));
    }
    float2 r; r.x = ax; r.y = ay;
    ((float2*)rst)[(size_t)node * 64 + lane] = r;
}

// ---------------- GEMM: C = pre(A) @ W + bias, striped column stats ----------------
// W hi/lo staged in LDS (XOR-swizzled); A (f32) streamed global->registers.
// Split: hi = trunc16(x) (v_perm pack), lo = trunc16(x - hi) (exact sub + perm pack).
// PRE==1: relu(a*x+c), coeffs per-lane from striped stats redistributed via __shfl.
// OUTBF==1: write C as bf16 (RNE), stats on the rounded values.

template <int PRE, int OUTBF>
__global__ __launch_bounds__(256, 2) void gemm_kernel(
    const float* __restrict__ A,
    const short* __restrict__ WtHi, const short* __restrict__ WtLo,
    const float* __restrict__ bias,
    const float* __restrict__ preStats, const float* __restrict__ preG,
    const float* __restrict__ preB,
    float* __restrict__ C, unsigned short* __restrict__ Cb,
    float* __restrict__ outStats, int N) {
    __shared__ short WsHi[128 * 128];
    __shared__ short WsLo[128 * 128];

    const int t = threadIdx.x;
    const int row0 = blockIdx.x * 128;
    const int w = t >> 6, lane = t & 63;
    const int quad = lane >> 4, l16 = lane & 15;
    const int sw = (l16 & 7) * 8;

    float aE = 1.f, cE = 0.f, aO = 1.f, cO = 0.f;
    if (PRE) {
        coeff_from_stats(preStats, preG, preB, lane * 2, N, aE, cE);
        coeff_from_stats(preStats, preG, preB, lane * 2 + 1, N, aO, cO);
    }

    // phase 1: A f32 loads (rows w*32+l16, w*32+16+l16)
    float4 af[2][4][2];
#pragma unroll
    for (int m = 0; m < 2; ++m) {
        int gr = row0 + w * 32 + m * 16 + l16;
        bool ok = gr < N;
        const float* Ar = A + (size_t)gr * 128;
#pragma unroll
        for (int kk = 0; kk < 4; ++kk) {
            int kb = kk * 32 + quad * 8;
            af[m][kk][0] = ok ? *(const float4*)(Ar + kb) : make_float4(0.f, 0.f, 0.f, 0.f);
            af[m][kk][1] = ok ? *(const float4*)(Ar + kb + 4) : make_float4(0.f, 0.f, 0.f, 0.f);
        }
    }

    // phase 2: stage W hi/lo into LDS, XOR-swizzled rows
#pragma unroll
    for (int i = 0; i < 8; ++i) {
        int ch = t + i * 256;
        int r = ch >> 4, k = (ch & 15) * 8;
        int d = r * 128 + (k ^ ((r & 7) * 8));
        *(short8*)(WsHi + d) = *(const short8*)(WtHi + r * 128 + k);
        *(short8*)(WsLo + d) = *(const short8*)(WtLo + r * 128 + k);
    }
    __syncthreads();

    // phase 3: BN + truncation split of A fragments (perm-packed)
    short8 fh[2][4], fl[2][4];
#pragma unroll
    for (int kk = 0; kk < 4; ++kk) {
        float a8[8], c8[8];
#pragma unroll
        for (int j = 0; j < 8; ++j) {
            if (PRE) {
                int col = kk * 32 + quad * 8 + j;
                int srcl = col >> 1;
                a8[j] = __shfl((j & 1) ? aO : aE, srcl, 64);
                c8[j] = __shfl((j & 1) ? cO : cE, srcl, 64);
            }
        }
#pragma unroll
        for (int m = 0; m < 2; ++m) {
            float x[8];
            *(float4*)(x) = af[m][kk][0];
            *(float4*)(x + 4) = af[m][kk][1];
            short8 h, lo;
#pragma unroll
            for (int j = 0; j < 4; ++j) {
                float x0 = x[2 * j], x1 = x[2 * j + 1];
                if (PRE) {
                    x0 = fmaxf(a8[2 * j] * x0 + c8[2 * j], 0.f);
                    x1 = fmaxf(a8[2 * j + 1] * x1 + c8[2 * j + 1], 0.f);
                }
                unsigned u0 = asu(x0), u1 = asu(x1);
                unsigned hp = __builtin_amdgcn_perm(u1, u0, 0x07060302u);
                float l0 = x0 - asf(u0 & 0xFFFF0000u);
                float l1 = x1 - asf(u1 & 0xFFFF0000u);
                unsigned lp = __builtin_amdgcn_perm(asu(l1), asu(l0), 0x07060302u);
                ((unsigned*)&h)[j] = hp;
                ((unsigned*)&lo)[j] = lp;
            }
            fh[m][kk] = h;
            fl[m][kk] = lo;
        }
    }

    f32x4 acc[2][8];
#pragma unroll
    for (int m = 0; m < 2; ++m)
#pragma unroll
        for (int n = 0; n < 8; ++n) acc[m][n] = (f32x4){0.f, 0.f, 0.f, 0.f};

#pragma unroll
    for (int kk = 0; kk < 4; ++kk) {
        int kb = kk * 32 + quad * 8;
        bf16x8 a0h = __builtin_bit_cast(bf16x8, fh[0][kk]);
        bf16x8 a1h = __builtin_bit_cast(bf16x8, fh[1][kk]);
        bf16x8 a0l = __builtin_bit_cast(bf16x8, fl[0][kk]);
        bf16x8 a1l = __builtin_bit_cast(bf16x8, fl[1][kk]);
#pragma unroll
        for (int n = 0; n < 8; ++n) {
            int woff = (n * 16 + l16) * 128 + (kb ^ sw);
            bf16x8 bh = __builtin_bit_cast(bf16x8, *(const short8*)(WsHi + woff));
            bf16x8 bl = __builtin_bit_cast(bf16x8, *(const short8*)(WsLo + woff));
            acc[0][n] = __builtin_amdgcn_mfma_f32_16x16x32_bf16(a0h, bh, acc[0][n], 0, 0, 0);
            acc[0][n] = __builtin_amdgcn_mfma_f32_16x16x32_bf16(a0l, bh, acc[0][n], 0, 0, 0);
            acc[0][n] = __builtin_amdgcn_mfma_f32_16x16x32_bf16(a0h, bl, acc[0][n], 0, 0, 0);
            acc[1][n] = __builtin_amdgcn_mfma_f32_16x16x32_bf16(a1h, bh, acc[1][n], 0, 0, 0);
            acc[1][n] = __builtin_amdgcn_mfma_f32_16x16x32_bf16(a1l, bh, acc[1][n], 0, 0, 0);
            acc[1][n] = __builtin_amdgcn_mfma_f32_16x16x32_bf16(a1h, bl, acc[1][n], 0, 0, 0);
        }
    }

    __syncthreads(); // all LDS reads done; WsHi reused below for stats reduction

    float bv[8];
#pragma unroll
    for (int n = 0; n < 8; ++n) bv[n] = bias[n * 16 + l16];
    float ls[8], lsq[8];
#pragma unroll
    for (int n = 0; n < 8; ++n) { ls[n] = 0.f; lsq[n] = 0.f; }
#pragma unroll
    for (int m = 0; m < 2; ++m) {
        int rbase = row0 + w * 32 + m * 16 + quad * 4;
#pragma unroll
        for (int n = 0; n < 8; ++n) {
            int colv = n * 16 + l16;
#pragma unroll
            for (int r = 0; r < 4; ++r) {
                int row = rbase + r;
                if (row < N) {
                    float val = acc[m][n][r] + bv[n];
                    if (OUTBF) {
                        short hb = f2bf(val);
                        float vr = bf2f(hb);
                        Cb[(size_t)row * 128 + colv] = (unsigned short)hb;
                        ls[n] += vr;
                        lsq[n] += vr * vr;
                    } else {
                        C[(size_t)row * 128 + colv] = val;
                        ls[n] += val;
                        lsq[n] += val * val;
                    }
                }
            }
        }
    }

    float* P = (float*)WsHi;
#pragma unroll
    for (int n = 0; n < 8; ++n) {
        float s = ls[n], q = lsq[n];
        s += __shfl_xor(s, 16, 64);
        s += __shfl_xor(s, 32, 64);
        q += __shfl_xor(q, 16, 64);
        q += __shfl_xor(q, 32, 64);
        if (quad == 0) {
            int colv = n * 16 + l16;
            P[w * 512 + colv] = s;
            P[w * 512 + 256 + colv] = q;
        }
    }
    __syncthreads();

    int stripe = blockIdx.x & 7;
    if (t < 128) {
        int col = t;
        float S = P[col] + P[512 + col] + P[1024 + col] + P[1536 + col];
        atomicAdd(&outStats[stripe * 256 + col], S);
    } else {
        int col = t - 128;
        float Q = P[256 + col] + P[768 + col] + P[1280 + col] + P[1792 + col];
        atomicAdd(&outStats[stripe * 256 + 128 + col], Q);
    }
}

// ---------------- stats of y = relu(a*x+c) over bf16 X (no materialization) ----------------

__global__ __launch_bounds__(256) void elt_kernel(
    const unsigned short* __restrict__ Xb,
    const float* __restrict__ inStats, const float* __restrict__ g, const float* __restrict__ bb,
    float* __restrict__ outStats, int N) {
    __shared__ float red[256 * 8];
    __shared__ float cf[2][128];
    int t = threadIdx.x;
    if (t < 128) {
        float a, c;
        coeff_from_stats(inStats, g, bb, t, N, a, c);
        cf[0][t] = a; cf[1][t] = c;
    }
    __syncthreads();
    int cg = t & 31;
    float a[4], c[4];
#pragma unroll
    for (int k = 0; k < 4; ++k) {
        a[k] = cf[0][cg * 4 + k];
        c[k] = cf[1][cg * 4 + k];
    }
    float sum[4] = {0.f, 0.f, 0.f, 0.f}, sq[4] = {0.f, 0.f, 0.f, 0.f};
    int total = N * 32;
    for (int i = blockIdx.x * 256 + t; i < total; i += gridDim.x * 256) {
        ushort4 u = ((const ushort4*)Xb)[i];
        float y0 = fmaxf(a[0] * bf2f((short)u.x) + c[0], 0.f);
        float y1 = fmaxf(a[1] * bf2f((short)u.y) + c[1], 0.f);
        float y2 = fmaxf(a[2] * bf2f((short)u.z) + c[2], 0.f);
        float y3 = fmaxf(a[3] * bf2f((short)u.w) + c[3], 0.f);
        sum[0] += y0; sq[0] += y0 * y0;
        sum[1] += y1; sq[1] += y1 * y1;
        sum[2] += y2; sq[2] += y2 * y2;
        sum[3] += y3; sq[3] += y3 * y3;
    }
#pragma unroll
    for (int k = 0; k < 4; ++k) { red[t * 8 + k] = sum[k]; red[t * 8 + 4 + k] = sq[k]; }
    __syncthreads();
    if (t < 32) {
        float S[4] = {0.f, 0.f, 0.f, 0.f}, Q[4] = {0.f, 0.f, 0.f, 0.f};
        for (int j = 0; j < 8; ++j) {
            int tt = t + 32 * j;
#pragma unroll
            for (int k = 0; k < 4; ++k) { S[k] += red[tt * 8 + k]; Q[k] += red[tt * 8 + 4 + k]; }
        }
        int stripe = blockIdx.x & 7;
#pragma unroll
        for (int k = 0; k < 4; ++k) {
            atomicAdd(&outStats[stripe * 256 + t * 4 + k], S[k]);
            atomicAdd(&outStats[stripe * 256 + 128 + t * 4 + k], Q[k]);
        }
    }
}

// ---------------- final: out = relu(a3*relu(a2*x+c2)+c3) from bf16 X ----------------

__global__ __launch_bounds__(256) void final_kernel(
    const unsigned short* __restrict__ Xb,
    const float* __restrict__ stats2, const float* __restrict__ g2, const float* __restrict__ b2v,
    const float* __restrict__ stats3, const float* __restrict__ g3, const float* __restrict__ b3v,
    float* __restrict__ out, int N) {
    __shared__ float cf[4][128];
    int t = threadIdx.x;
    if (t < 128) {
        float a, c;
        coeff_from_stats(stats2, g2, b2v, t, N, a, c);
        cf[0][t] = a; cf[1][t] = c;
        coeff_from_stats(stats3, g3, b3v, t, N, a, c);
        cf[2][t] = a; cf[3][t] = c;
    }
    __syncthreads();
    int cg = t & 31;
    float a2[4], c2[4], a3[4], c3[4];
#pragma unroll
    for (int k = 0; k < 4; ++k) {
        int colv = cg * 4 + k;
        a2[k] = cf[0][colv]; c2[k] = cf[1][colv];
        a3[k] = cf[2][colv]; c3[k] = cf[3][colv];
    }
    int total = N * 32;
    for (int i = blockIdx.x * 256 + t; i < total; i += gridDim.x * 256) {
        ushort4 u = ((const ushort4*)Xb)[i];
        float4 y;
        y.x = fmaxf(a3[0] * fmaxf(a2[0] * bf2f((short)u.x) + c2[0], 0.f) + c3[0], 0.f);
        y.y = fmaxf(a3[1] * fmaxf(a2[1] * bf2f((short)u.y) + c2[1], 0.f) + c3[1], 0.f);
        y.z = fmaxf(a3[2] * fmaxf(a2[2] * bf2f((short)u.z) + c2[2], 0.f) + c3[2], 0.f);
        y.w = fmaxf(a3[3] * fmaxf(a2[3] * bf2f((short)u.w) + c2[3], 0.f) + c3[3], 0.f);
        ((float4*)out)[i] = y;
    }
}

// ---------------- launch ----------------

extern "C" void kernel_launch(void* const* d_in, const int* in_sizes, int n_in,
                              void* d_out, int out_size, void* d_ws, size_t ws_size,
                              hipStream_t stream) {
    const float* h0   = (const float*)d_in[0];
    const int*   src  = (const int*)d_in[1];
    const int*   dst  = (const int*)d_in[2];
    const float* W1   = (const float*)d_in[3];
    const float* b1   = (const float*)d_in[4];
    const float* W2   = (const float*)d_in[5];
    const float* b2   = (const float*)d_in[6];
    const float* bn1g = (const float*)d_in[7];
    const float* bn1b = (const float*)d_in[8];
    const float* bn2g = (const float*)d_in[9];
    const float* bn2b = (const float*)d_in[10];
    const float* bn3g = (const float*)d_in[11];
    const float* bn3b = (const float*)d_in[12];
    const int N = in_sizes[0] / 128;
    const int E = in_sizes[1];
    const int nb = (N + 127) >> CSR_SHIFT; // buckets (<= NBMAX for N <= 65536)

    char* ws = (char*)d_ws;
    size_t off = 0;
    auto alloc = [&](size_t bytes) {
        void* p = ws + off;
        off = (off + bytes + 255) & ~(size_t)255;
        return p;
    };
    float* stats        = (float*)alloc((size_t)5 * 3 * 8 * 256 * sizeof(float)); // striped
    int*   bucketCnt    = (int*)alloc((size_t)NBMAX * 4);
    int*   bucketBase   = (int*)alloc((size_t)(NBMAX + 1) * 4);
    int*   bucketCursor = (int*)alloc((size_t)NBMAX * 4);
    int*   rowptr       = (int*)alloc((size_t)(N + 1) * 4);
    int*   colidx       = (int*)alloc((size_t)E * 4);
    uint2* pairs        = (uint2*)alloc((size_t)E * 8);
    short* WtHi         = (short*)alloc((size_t)10 * 16384 * 2);
    short* WtLo         = (short*)alloc((size_t)10 * 16384 * 2);
    float* buf0         = (float*)alloc((size_t)N * 128 * 4);       // rst (f32)
    float* buf1         = (float*)alloc((size_t)N * 128 * 4);       // x1 (f32)
    unsigned short* xbf = (unsigned short*)alloc((size_t)N * 128 * 2); // h0/x2 (bf16)

    auto statsBase = [&](int l, int which) { return stats + ((size_t)(l * 3 + which)) * 8 * 256; };

    const int nstats = 5 * 3 * 8 * 256;
    int zmax = (N > nstats ? N : nstats);
    zero_kernel<<<(zmax + 255) / 256, 256, 0, stream>>>(stats, nstats, bucketCnt, nb);
    h2bf_kernel<<<(N * 32 + 255) / 256, 256, 0, stream>>>(h0, xbf, N * 32);
    tw_kernel<<<(10 * 16384 + 255) / 256, 256, 0, stream>>>(W1, W2, WtHi, WtLo);

    const int chunk = 4096;
    const int chunkGrid = (E + chunk - 1) / chunk;
    bcount_kernel<<<chunkGrid, 256, 0, stream>>>(dst, bucketCnt, E, nb, chunk);
    bscan_kernel<<<1, 512, 0, stream>>>(bucketCnt, bucketBase, bucketCursor, rowptr, nb, N, E);
    bscatter_kernel<<<chunkGrid, 256, 0, stream>>>(src, dst, bucketCursor, pairs, E, nb, chunk);
    bbuild_kernel<<<nb, 256, 0, stream>>>(pairs, bucketBase, rowptr, colidx, N);

    const int gemmGrid = (N + 127) / 128;
    const int aggGrid = (N + 3) / 4;
    for (int l = 0; l < 5; ++l) {
        if (l == 0) {
            agg_kernel<0><<<aggGrid, 256, 0, stream>>>(
                xbf, rowptr, colidx,
                nullptr, nullptr, nullptr, nullptr, nullptr, nullptr,
                buf0, N);
        } else {
            int lp = l - 1;
            agg_kernel<1><<<aggGrid, 256, 0, stream>>>(
                xbf, rowptr, colidx,
                statsBase(lp, 1), bn2g + lp * 128, bn2b + lp * 128,
                statsBase(lp, 2), bn3g + lp * 128, bn3b + lp * 128,
                buf0, N);
        }
        gemm_kernel<0, 0><<<gemmGrid, 256, 0, stream>>>(
            buf0, WtHi + l * 16384, WtLo + l * 16384, b1 + l * 128,
            nullptr, nullptr, nullptr,
            buf1, nullptr, statsBase(l, 0), N);
        gemm_kernel<1, 1><<<gemmGrid, 256, 0, stream>>>(
            buf1, WtHi + (5 + l) * 16384, WtLo + (5 + l) * 16384, b2 + l * 128,
            statsBase(l, 0), bn1g + l * 128, bn1b + l * 128,
            nullptr, xbf, statsBase(l, 1), N);
        elt_kernel<<<256, 256, 0, stream>>>(
            xbf, statsBase(l, 1), bn2g + l * 128, bn2b + l * 128,
            statsBase(l, 2), N);
    }
    final_kernel<<<512, 256, 0, stream>>>(
        xbf,
        statsBase(4, 1), bn2g + 4 * 128, bn2b + 4 * 128,
        statsBase(4, 2), bn3g + 4 * 128, bn3b + 4 * 128,
        (float*)d_out, N);
}